// Round 2
// baseline (117.680 us; speedup 1.0000x reference)
//
#include <hip/hip_runtime.h>

#define C_IN   8
#define CH     8
#define Hh     128
#define Ww     192
#define HW     (Hh*Ww)
#define NINST  128
#define NPAR   169
#define OH     256
#define OW     384
#define BAND   16          // logits rows produced as output per block (32 out rows)
#define LROWS  18          // band + top halo + bottom clamp row
#define NBAND  (Hh/BAND)   // 8

// Param layout per instance (169 floats):
// w0: [0,80) (8x10) | w1: [80,144) (8x8) | w2: [144,152) (1x8)
// b0: [152,160) | b1: [160,168) | b2: [168]

__global__ __launch_bounds__(192, 3)
void fused_maskhead_kernel(const float* __restrict__ feats,
                           const float* __restrict__ params,
                           const float* __restrict__ locs,
                           const int* __restrict__ im_inds,
                           const int* __restrict__ fpn,
                           float* __restrict__ out)
{
    __shared__ float sw[NPAR];
    __shared__ float sl[LROWS][Ww];   // 18*192*4 = 13824 B logits tile

    const int inst = blockIdx.x;
    const int band = blockIdx.y;
    const int x    = threadIdx.x;     // 0..191 — one column per thread
    const int r0   = band * BAND;

    if (x < NPAR) sw[x] = params[inst * NPAR + x];

    const float ix = locs[inst*2 + 0];
    const float iy = locs[inst*2 + 1];
    const float inv_soi = 1.0f / (float)(64 << fpn[inst]);
    const float* fbase = feats + (size_t)im_inds[inst] * (C_IN * HW);

    const float rx = (ix - (float)(x * 8 + 4)) * inv_soi;

    __syncthreads();

    // ---- MLP: fill sl[i] = logits(row clamp(r0-1+i, 0, 127)) for i in [0,18)
    // 3 fixed batches of 6 rows -> all activation arrays statically indexed.
    #pragma unroll
    for (int i0 = 0; i0 < LROWS; i0 += 6) {
        float f[6][C_IN];
        float ry[6];
        #pragma unroll
        for (int k = 0; k < 6; ++k) {
            const int sr = min(max(r0 - 1 + i0 + k, 0), Hh - 1);
            ry[k] = (iy - (float)(sr * 8 + 4)) * inv_soi;
            const float* fp = fbase + sr * Ww + x;
            #pragma unroll
            for (int c = 0; c < C_IN; ++c) f[k][c] = fp[c * HW];
        }

        float h1[6][CH];
        #pragma unroll
        for (int o = 0; o < CH; ++o) {
            const float w0 = sw[o*10 + 0];
            const float w1 = sw[o*10 + 1];
            float wc[C_IN];
            #pragma unroll
            for (int c = 0; c < C_IN; ++c) wc[c] = sw[o*10 + 2 + c];
            const float b = sw[152 + o];
            #pragma unroll
            for (int k = 0; k < 6; ++k) {
                float a = b;
                a = fmaf(w0, rx,    a);
                a = fmaf(w1, ry[k], a);
                #pragma unroll
                for (int c = 0; c < C_IN; ++c) a = fmaf(wc[c], f[k][c], a);
                h1[k][o] = fmaxf(a, 0.0f);
            }
        }

        float h2[6][CH];
        #pragma unroll
        for (int o = 0; o < CH; ++o) {
            float wc[CH];
            #pragma unroll
            for (int c = 0; c < CH; ++c) wc[c] = sw[80 + o*8 + c];
            const float b = sw[160 + o];
            #pragma unroll
            for (int k = 0; k < 6; ++k) {
                float a = b;
                #pragma unroll
                for (int c = 0; c < CH; ++c) a = fmaf(wc[c], h1[k][c], a);
                h2[k][o] = fmaxf(a, 0.0f);
            }
        }

        {
            float wc[CH];
            #pragma unroll
            for (int c = 0; c < CH; ++c) wc[c] = sw[144 + c];
            const float b = sw[168];
            #pragma unroll
            for (int k = 0; k < 6; ++k) {
                float z = b;
                #pragma unroll
                for (int c = 0; c < CH; ++c) z = fmaf(wc[c], h2[k][c], z);
                sl[i0 + k][x] = z;
            }
        }
    }

    __syncthreads();

    // ---- 2x aligned bilinear from LDS tile.
    // out[oy][ox] = u[max(oy-1,0)][max(ox-1,0)], u = bilinear upsample w/ edge pad.
    // LDS row i holds source row clamp(r0-1+i, 0, 127); y1 reads are exact
    // (row 17 = clamp(r0+16,127) matches min(y0+1,127) when needed).
    float2* outf2 = (float2*)out;
    const int xm1 = max(x - 1, 0);

    #pragma unroll 4
    for (int j = 0; j < 2*BAND; ++j) {
        const int oy  = 2*r0 + j;
        const int ay  = max(oy - 1, 0);
        const int y0l = (ay >> 1) - r0 + 1;          // in [0,16]
        const int y1l = y0l + 1;                      // in [1,17]
        const float fy = (ay & 1) ? 0.5f : 0.0f;

        const float t01 = sl[y0l][x];
        const float t00 = sl[y0l][xm1];
        const float t11 = sl[y1l][x];
        const float t10 = sl[y1l][xm1];

        const float rma = fmaf(fy, t10 - t00, t00);
        const float rmb = fmaf(fy, t11 - t01, t01);

        float2 v;
        v.x = 0.5f * (rma + rmb);
        v.y = rmb;
        outf2[((size_t)inst * OH + oy) * (OW/2) + x] = v;
    }
}

extern "C" void kernel_launch(void* const* d_in, const int* in_sizes, int n_in,
                              void* d_out, int out_size, void* d_ws, size_t ws_size,
                              hipStream_t stream) {
    const float* feats  = (const float*)d_in[0];
    const float* params = (const float*)d_in[1];
    const float* locs   = (const float*)d_in[2];
    const int*   im     = (const int*)d_in[3];
    const int*   fpn    = (const int*)d_in[4];
    float* out = (float*)d_out;

    dim3 grid(NINST, NBAND);   // 128 x 8 = 1024 blocks
    fused_maskhead_kernel<<<grid, 192, 0, stream>>>(feats, params, locs, im, fpn, out);
}

// Round 3
// 110.220 us; speedup vs baseline: 1.0677x; 1.0677x over previous
//
#include <hip/hip_runtime.h>

#define C_IN   8
#define CH     8
#define Hh     128
#define Ww     192
#define HW     (Hh*Ww)
#define NINST  128
#define NPAR   169
#define OH     256
#define OW     384
#define BAND   8           // source rows owned per block
#define LROWS  (BAND+1)    // + 1 bottom halo row
#define NBAND  (Hh/BAND)   // 16

typedef float f32x2 __attribute__((ext_vector_type(2)));

// Param layout per instance (169 floats):
// w0: [0,80) (8x10) | w1: [80,144) (8x8) | w2: [144,152) (1x8)
// b0: [152,160) | b1: [160,168) | b2: [168]
//
// Output mapping (verified partition): block(band) computes source rows
// [r0, r0+8] and writes out rows [2r0+2, 2r0+18); band 0 additionally writes
// rows 0-1 (they only need source row 0); band 15 clips at 256. Out row oy
// needs y0=(max(oy-1,0))>>1 in [r0, r0+8] -> all in the block's LDS tile.

__global__ __launch_bounds__(192, 6)
void fused_maskhead_kernel(const float* __restrict__ feats,
                           const float* __restrict__ params,
                           const float* __restrict__ locs,
                           const int* __restrict__ im_inds,
                           const int* __restrict__ fpn,
                           float* __restrict__ out)
{
    __shared__ float sw[NPAR];
    __shared__ float sl[LROWS][Ww];   // 9*192*4 = 6912 B

    const int inst = blockIdx.x;
    const int band = blockIdx.y;
    const int x    = threadIdx.x;     // 0..191 — one column per thread
    const int r0   = band * BAND;

    if (x < NPAR) sw[x] = params[inst * NPAR + x];

    const float ix = locs[inst*2 + 0];
    const float iy = locs[inst*2 + 1];
    const float inv_soi = 1.0f / (float)(64 << fpn[inst]);
    const float* fbase = feats + (size_t)im_inds[inst] * (C_IN * HW) + x;

    const float rx = (ix - (float)(x * 8 + 4)) * inv_soi;

    __syncthreads();

    // ---- MLP: sl[i] = logits(row min(r0+i, 127)) for i in [0,9)
    // 3 fixed batches of 3 rows -> all activation arrays statically indexed.
    #pragma unroll
    for (int i0 = 0; i0 < LROWS; i0 += 3) {
        float f[3][C_IN];
        float ry[3];
        #pragma unroll
        for (int k = 0; k < 3; ++k) {
            const int sr = min(r0 + i0 + k, Hh - 1);
            ry[k] = (iy - (float)(sr * 8 + 4)) * inv_soi;
            const float* fp = fbase + sr * Ww;
            #pragma unroll
            for (int c = 0; c < C_IN; ++c) f[k][c] = fp[c * HW];
        }

        float h1[3][CH];
        #pragma unroll
        for (int o = 0; o < CH; ++o) {
            const float w0 = sw[o*10 + 0];
            const float w1 = sw[o*10 + 1];
            float wc[C_IN];
            #pragma unroll
            for (int c = 0; c < C_IN; ++c) wc[c] = sw[o*10 + 2 + c];
            const float b = sw[152 + o];
            #pragma unroll
            for (int k = 0; k < 3; ++k) {
                float a = b;
                a = fmaf(w0, rx,    a);
                a = fmaf(w1, ry[k], a);
                #pragma unroll
                for (int c = 0; c < C_IN; ++c) a = fmaf(wc[c], f[k][c], a);
                h1[k][o] = fmaxf(a, 0.0f);
            }
        }

        float h2[3][CH];
        #pragma unroll
        for (int o = 0; o < CH; ++o) {
            float wc[CH];
            #pragma unroll
            for (int c = 0; c < CH; ++c) wc[c] = sw[80 + o*8 + c];
            const float b = sw[160 + o];
            #pragma unroll
            for (int k = 0; k < 3; ++k) {
                float a = b;
                #pragma unroll
                for (int c = 0; c < CH; ++c) a = fmaf(wc[c], h1[k][c], a);
                h2[k][o] = fmaxf(a, 0.0f);
            }
        }

        {
            float wc[CH];
            #pragma unroll
            for (int c = 0; c < CH; ++c) wc[c] = sw[144 + c];
            const float b = sw[168];
            #pragma unroll
            for (int k = 0; k < 3; ++k) {
                float z = b;
                #pragma unroll
                for (int c = 0; c < CH; ++c) z = fmaf(wc[c], h2[k][c], z);
                sl[i0 + k][x] = z;
            }
        }
    }

    __syncthreads();

    // ---- 2x aligned bilinear from LDS tile, non-temporal float2 stores.
    f32x2* outf2 = (f32x2*)out;
    const int xm1 = max(x - 1, 0);
    const int jlo = (band == 0) ? -2 : 0;
    const int jhi = (band == NBAND - 1) ? 2*BAND - 2 : 2*BAND;

    #pragma unroll 4
    for (int j = jlo; j < jhi; ++j) {
        const int oy  = 2*r0 + 2 + j;
        const int ay  = max(oy - 1, 0);
        const int y0l = (ay >> 1) - r0;              // in [0, 8]
        const int y1l = min(y0l + 1, BAND);          // clamp only hit when fy==0
        const float fy = (ay & 1) ? 0.5f : 0.0f;

        const float t01 = sl[y0l][x];
        const float t00 = sl[y0l][xm1];
        const float t11 = sl[y1l][x];
        const float t10 = sl[y1l][xm1];

        const float rma = fmaf(fy, t10 - t00, t00);
        const float rmb = fmaf(fy, t11 - t01, t01);

        f32x2 v;
        v.x = 0.5f * (rma + rmb);
        v.y = rmb;
        __builtin_nontemporal_store(v, &outf2[((size_t)inst * OH + oy) * (OW/2) + x]);
    }
}

extern "C" void kernel_launch(void* const* d_in, const int* in_sizes, int n_in,
                              void* d_out, int out_size, void* d_ws, size_t ws_size,
                              hipStream_t stream) {
    const float* feats  = (const float*)d_in[0];
    const float* params = (const float*)d_in[1];
    const float* locs   = (const float*)d_in[2];
    const int*   im     = (const int*)d_in[3];
    const int*   fpn    = (const int*)d_in[4];
    float* out = (float*)d_out;

    dim3 grid(NINST, NBAND);   // 128 x 16 = 2048 blocks
    fused_maskhead_kernel<<<grid, 192, 0, stream>>>(feats, params, locs, im, fpn, out);
}

// Round 4
// 34.551 us; speedup vs baseline: 3.4060x; 3.1901x over previous
//
#include <hip/hip_runtime.h>

#define C_IN   8
#define CH     8
#define Hh     128
#define Ww     192
#define HW     (Hh*Ww)
#define NINST  128
#define NPAR   169
#define OH     256
#define OW     384
#define IPB    8             // instances per block
#define NIG    (NINST/IPB)   // 16 instance groups
#define NRG    64            // row groups: source rows [2rg, 2rg+2] (2 owned + 1 halo)

typedef float f32x2 __attribute__((ext_vector_type(2)));

// Param layout per instance (169 floats):
// w0: [0,80) (8x10) | w1: [80,144) (8x8) | w2: [144,152) (1x8)
// b0: [152,160) | b1: [160,168) | b2: [168]
//
// Output mapping (verified in R3): block with source rows [r0, r0+2] writes
// out rows [2r0+2, 2r0+6); rg==0 adds rows {0,1}; rg==63 clips at 256.

__global__ __launch_bounds__(192, 3)
void fused_maskhead_kernel(const float* __restrict__ feats,
                           const float* __restrict__ params,
                           const float* __restrict__ locs,
                           const int* __restrict__ im_inds,
                           const int* __restrict__ fpn,
                           float* __restrict__ out)
{
    __shared__ float sw[IPB * NPAR];   // 5408 B
    __shared__ float sl[3][Ww];        // 2304 B logits tile

    const int rg = blockIdx.x;         // 0..63
    const int ig = blockIdx.y;         // 0..15
    const int x  = threadIdx.x;        // 0..191 — one column per thread
    const int r0 = rg * 2;

    // stage 8 instances' params (contiguous -> coalesced)
    for (int j = x; j < IPB * NPAR; j += 192)
        sw[j] = params[ig * IPB * NPAR + j];

    // feats for BOTH images, rows r0..r0+2 (row clamp at 127) -> 48 regs
    float f0[3][C_IN], f1[3][C_IN];
    #pragma unroll
    for (int k = 0; k < 3; ++k) {
        const int sr = min(r0 + k, Hh - 1);
        const float* p0 = feats + sr * Ww + x;
        #pragma unroll
        for (int c = 0; c < C_IN; ++c) {
            f0[k][c] = p0[c * HW];
            f1[k][c] = p0[C_IN * HW + c * HW];
        }
    }

    __syncthreads();

    const int xm1 = max(x - 1, 0);
    f32x2* outf2 = (f32x2*)out;
    const int jlo = (rg == 0) ? -2 : 0;
    const int jhi = (rg == NRG - 1) ? 2 : 4;

    // run one image's instances with statically-bound feat registers
    auto run = [&](const float (&f)[3][C_IN], const int img) {
        for (int j = 0; j < IPB; ++j) {
            const int inst = ig * IPB + j;
            if (im_inds[inst] != img) continue;   // block-uniform -> barriers safe

            const float* W = sw + j * NPAR;
            const float ixv = locs[inst * 2 + 0];
            const float iyv = locs[inst * 2 + 1];
            const float inv_soi = 1.0f / (float)(64 << fpn[inst]);
            const float rx = (ixv - (float)(x * 8 + 4)) * inv_soi;
            float ry[3];
            #pragma unroll
            for (int k = 0; k < 3; ++k)
                ry[k] = (iyv - (float)(min(r0 + k, Hh - 1) * 8 + 4)) * inv_soi;

            float h1[3][CH];
            #pragma unroll
            for (int o = 0; o < CH; ++o) {
                const float b  = W[152 + o];
                const float w0 = W[o * 10 + 0];
                const float w1 = W[o * 10 + 1];
                #pragma unroll
                for (int k = 0; k < 3; ++k) {
                    float a = fmaf(w0, rx, fmaf(w1, ry[k], b));
                    #pragma unroll
                    for (int c = 0; c < C_IN; ++c)
                        a = fmaf(W[o * 10 + 2 + c], f[k][c], a);
                    h1[k][o] = fmaxf(a, 0.0f);
                }
            }

            float h2[3][CH];
            #pragma unroll
            for (int o = 0; o < CH; ++o) {
                const float b = W[160 + o];
                #pragma unroll
                for (int k = 0; k < 3; ++k) {
                    float a = b;
                    #pragma unroll
                    for (int c = 0; c < CH; ++c)
                        a = fmaf(W[80 + o * 8 + c], h1[k][c], a);
                    h2[k][o] = fmaxf(a, 0.0f);
                }
            }

            #pragma unroll
            for (int k = 0; k < 3; ++k) {
                float z = W[168];
                #pragma unroll
                for (int c = 0; c < CH; ++c)
                    z = fmaf(W[144 + c], h2[k][c], z);
                sl[k][x] = z;
            }

            __syncthreads();

            #pragma unroll
            for (int jj = jlo; jj < jhi; ++jj) {
                const int oy  = r0 * 2 + 2 + jj;
                const int ay  = max(oy - 1, 0);
                const int y0l = (ay >> 1) - r0;        // 0..2
                const int y1l = min(y0l + 1, 2);       // clamp only hit when fy==0
                const float fy = (ay & 1) ? 0.5f : 0.0f;

                const float t01 = sl[y0l][x];
                const float t00 = sl[y0l][xm1];
                const float t11 = sl[y1l][x];
                const float t10 = sl[y1l][xm1];

                const float rma = fmaf(fy, t10 - t00, t00);
                const float rmb = fmaf(fy, t11 - t01, t01);

                f32x2 v;
                v.x = 0.5f * (rma + rmb);
                v.y = rmb;
                outf2[((size_t)inst * OH + oy) * (OW / 2) + x] = v;
            }

            __syncthreads();   // before next instance overwrites sl
        }
    };

    run(f0, 0);
    run(f1, 1);
}

extern "C" void kernel_launch(void* const* d_in, const int* in_sizes, int n_in,
                              void* d_out, int out_size, void* d_ws, size_t ws_size,
                              hipStream_t stream) {
    const float* feats  = (const float*)d_in[0];
    const float* params = (const float*)d_in[1];
    const float* locs   = (const float*)d_in[2];
    const int*   im     = (const int*)d_in[3];
    const int*   fpn    = (const int*)d_in[4];
    float* out = (float*)d_out;

    dim3 grid(NRG, NIG);   // 64 x 16 = 1024 blocks
    fused_maskhead_kernel<<<grid, 192, 0, stream>>>(feats, params, locs, im, fpn, out);
}

// Round 5
// 31.209 us; speedup vs baseline: 3.7707x; 1.1071x over previous
//
#include <hip/hip_runtime.h>

#define C_IN   8
#define CH     8
#define Hh     128
#define Ww     192
#define HW     (Hh*Ww)
#define NINST  128
#define NPAR   169
#define OH     256
#define OW     384
#define B      4             // owned source rows per block
#define RT     (B+1)         // computed rows (incl. bottom halo)
#define NRG    (Hh/B)        // 32 row groups
#define IPB    2             // instances per block
#define NIG    (NINST/IPB)   // 64
#define WSTR   192           // packed LDS floats per instance

typedef float f32x2 __attribute__((ext_vector_type(2)));
typedef float f32x4 __attribute__((ext_vector_type(4)));

// Packed per-instance LDS layout (16B-aligned base, WSTR=192 floats):
//   [0,96):    w0 as [8][12] (10 used, 2 pad)  -> 3x ds_read_b128 per row
//   [96,160):  w1 as [8][8]                    -> 2x b128 per row
//   [160,168): w2[8]                           -> 2x b128
//   [168,176): b0[8]   [176,184): b1[8]   [184]: b2
//
// Output mapping (verified R3/R4): block with source rows [r0, r0+B] writes
// out rows [2r0+2, 2r0+2+2B); rg==0 adds rows {0,1}; rg==NRG-1 clips at 256.

__global__ __launch_bounds__(192, 3)
void fused_maskhead_kernel(const float* __restrict__ feats,
                           const float* __restrict__ params,
                           const float* __restrict__ locs,
                           const int* __restrict__ im_inds,
                           const int* __restrict__ fpn,
                           float* __restrict__ out)
{
    __shared__ __align__(16) float sw[IPB * WSTR];   // 1536 B
    __shared__ float sl[IPB][RT][Ww];                // 7680 B

    const int rg = blockIdx.x;        // 0..31
    const int ig = blockIdx.y;        // 0..63
    const int x  = threadIdx.x;       // 0..191 — one column per thread
    const int r0 = rg * B;

    // stage + repack params (coalesced global read, remapped LDS write)
    for (int j = x; j < IPB * NPAR; j += 192) {
        const int i = j / NPAR;
        const int r = j - i * NPAR;
        int dst;
        if (r < 80)       { const int o = r / 10; dst = o * 12 + (r - o * 10); }
        else if (r < 144) dst = 96  + (r - 80);
        else if (r < 152) dst = 160 + (r - 144);
        else if (r < 160) dst = 168 + (r - 152);
        else if (r < 168) dst = 176 + (r - 160);
        else              dst = 184;
        sw[i * WSTR + dst] = params[(ig * IPB + i) * NPAR + r];
    }

    __syncthreads();

    const int xm1 = max(x - 1, 0);
    f32x2* outf2 = (f32x2*)out;
    const int jlo = (rg == 0) ? -2 : 0;
    const int jhi = (rg == NRG - 1) ? 2 * B - 2 : 2 * B;

    float f[RT][C_IN];
    int cur_img = -1;

    #pragma unroll
    for (int ii = 0; ii < IPB; ++ii) {
        const int inst = ig * IPB + ii;
        const int img  = im_inds[inst];
        if (img != cur_img) {          // block-uniform branch
            cur_img = img;
            const float* fb = feats + (size_t)img * (C_IN * HW) + x;
            #pragma unroll
            for (int k = 0; k < RT; ++k) {
                const int sr = min(r0 + k, Hh - 1);
                #pragma unroll
                for (int c = 0; c < C_IN; ++c)
                    f[k][c] = fb[c * HW + sr * Ww];
            }
        }

        const float* W = sw + ii * WSTR;
        const float ixv = locs[inst * 2 + 0];
        const float iyv = locs[inst * 2 + 1];
        const float inv_soi = 1.0f / (float)(64 << fpn[inst]);
        const float rx = (ixv - (float)(x * 8 + 4)) * inv_soi;
        float ry[RT];
        #pragma unroll
        for (int k = 0; k < RT; ++k)
            ry[k] = (iyv - (float)(min(r0 + k, Hh - 1) * 8 + 4)) * inv_soi;

        // ---- layer 1 (10 -> 8), b128 weight reads
        float h1[RT][CH];
        #pragma unroll
        for (int o = 0; o < CH; ++o) {
            const f32x4 wa = *(const f32x4*)(W + o * 12 + 0);
            const f32x4 wb = *(const f32x4*)(W + o * 12 + 4);
            const f32x4 wc = *(const f32x4*)(W + o * 12 + 8);   // .z/.w pad
            const float bo = W[168 + o];
            #pragma unroll
            for (int k = 0; k < RT; ++k) {
                float a = fmaf(wa.x, rx, fmaf(wa.y, ry[k], bo));
                a = fmaf(wa.z, f[k][0], a);
                a = fmaf(wa.w, f[k][1], a);
                a = fmaf(wb.x, f[k][2], a);
                a = fmaf(wb.y, f[k][3], a);
                a = fmaf(wb.z, f[k][4], a);
                a = fmaf(wb.w, f[k][5], a);
                a = fmaf(wc.x, f[k][6], a);
                a = fmaf(wc.y, f[k][7], a);
                h1[k][o] = fmaxf(a, 0.0f);
            }
        }

        // ---- layer 2 (8 -> 8)
        float h2[RT][CH];
        #pragma unroll
        for (int o = 0; o < CH; ++o) {
            const f32x4 wa = *(const f32x4*)(W + 96 + o * 8 + 0);
            const f32x4 wb = *(const f32x4*)(W + 96 + o * 8 + 4);
            const float bo = W[176 + o];
            #pragma unroll
            for (int k = 0; k < RT; ++k) {
                float a = bo;
                a = fmaf(wa.x, h1[k][0], a);
                a = fmaf(wa.y, h1[k][1], a);
                a = fmaf(wa.z, h1[k][2], a);
                a = fmaf(wa.w, h1[k][3], a);
                a = fmaf(wb.x, h1[k][4], a);
                a = fmaf(wb.y, h1[k][5], a);
                a = fmaf(wb.z, h1[k][6], a);
                a = fmaf(wb.w, h1[k][7], a);
                h2[k][o] = fmaxf(a, 0.0f);
            }
        }

        // ---- layer 3 (8 -> 1)
        {
            const f32x4 wa = *(const f32x4*)(W + 160);
            const f32x4 wb = *(const f32x4*)(W + 164);
            const float bo = W[184];
            #pragma unroll
            for (int k = 0; k < RT; ++k) {
                float z = bo;
                z = fmaf(wa.x, h2[k][0], z);
                z = fmaf(wa.y, h2[k][1], z);
                z = fmaf(wa.z, h2[k][2], z);
                z = fmaf(wa.w, h2[k][3], z);
                z = fmaf(wb.x, h2[k][4], z);
                z = fmaf(wb.y, h2[k][5], z);
                z = fmaf(wb.z, h2[k][6], z);
                z = fmaf(wb.w, h2[k][7], z);
                sl[ii][k][x] = z;
            }
        }

        __syncthreads();   // sl[ii] visible; sl[ii^1] untouched (double buffer)

        // ---- 2x aligned bilinear from LDS tile
        #pragma unroll
        for (int jj = jlo; jj < jhi; ++jj) {
            const int oy  = 2 * r0 + 2 + jj;
            const int ay  = max(oy - 1, 0);
            const int y0l = (ay >> 1) - r0;            // 0..B
            const int y1l = min(y0l + 1, B);           // clamp only when fy==0
            const float fy = (ay & 1) ? 0.5f : 0.0f;

            const float t01 = sl[ii][y0l][x];
            const float t00 = sl[ii][y0l][xm1];
            const float t11 = sl[ii][y1l][x];
            const float t10 = sl[ii][y1l][xm1];

            const float rma = fmaf(fy, t10 - t00, t00);
            const float rmb = fmaf(fy, t11 - t01, t01);

            f32x2 v;
            v.x = 0.5f * (rma + rmb);
            v.y = rmb;
            outf2[((size_t)inst * OH + oy) * (OW / 2) + x] = v;
        }
    }
}

extern "C" void kernel_launch(void* const* d_in, const int* in_sizes, int n_in,
                              void* d_out, int out_size, void* d_ws, size_t ws_size,
                              hipStream_t stream) {
    const float* feats  = (const float*)d_in[0];
    const float* params = (const float*)d_in[1];
    const float* locs   = (const float*)d_in[2];
    const int*   im     = (const int*)d_in[3];
    const int*   fpn    = (const int*)d_in[4];
    float* out = (float*)d_out;

    dim3 grid(NRG, NIG);   // 32 x 64 = 2048 blocks
    fused_maskhead_kernel<<<grid, 192, 0, stream>>>(feats, params, locs, im, fpn, out);
}